// Round 13
// baseline (452.587 us; speedup 1.0000x reference)
//
#include <hip/hip_runtime.h>
#include <math.h>

#define NB    4
#define NPTS  2048
#define ROWS  (NB*NPTS)   // 8192
#define CIN   64
#define COUT  256
#define KNBR  21
#define NHEADS 7
#define WCH   64
#define DSH   32
#define LOG2E 1.4426950408889634f

typedef __attribute__((ext_vector_type(8))) short short8;
typedef __attribute__((ext_vector_type(4))) float floatx4;

__device__ __forceinline__ ushort f2bf(float x) {
    unsigned u = __float_as_uint(x);
    u += 0x7fffu + ((u >> 16) & 1u);   // RNE
    return (ushort)(u >> 16);
}

// DPP rotate within 16-lane row (VALU, no LDS pipe)
template<int N>
__device__ __forceinline__ float dpp_ror16(float x) {
    return __int_as_float(__builtin_amdgcn_update_dpp(
        0, __float_as_int(x), 0x120 | N, 0xF, 0xF, true));
}
__device__ __forceinline__ float dpp_max16(float x) {
    x = fmaxf(x, dpp_ror16<1>(x));
    x = fmaxf(x, dpp_ror16<2>(x));
    x = fmaxf(x, dpp_ror16<4>(x));
    x = fmaxf(x, dpp_ror16<8>(x));
    return x;
}
__device__ __forceinline__ float dpp_sum16(float x) {
    x += dpp_ror16<1>(x);
    x += dpp_ror16<2>(x);
    x += dpp_ror16<4>(x);
    x += dpp_ror16<8>(x);
    return x;
}

// wave64 u32 min-reduce via DPP chain; broadcast via readlane(63)
template<int CTRL, int RMASK>
__device__ __forceinline__ unsigned dpp_umin_step(unsigned x) {
    unsigned t = (unsigned)__builtin_amdgcn_update_dpp((int)x, (int)x, CTRL, RMASK, 0xF, false);
    return (t < x) ? t : x;
}
__device__ __forceinline__ unsigned wave_min_u32(unsigned x) {
    x = dpp_umin_step<0x111, 0xF>(x);
    x = dpp_umin_step<0x112, 0xF>(x);
    x = dpp_umin_step<0x114, 0xF>(x);
    x = dpp_umin_step<0x118, 0xF>(x);
    x = dpp_umin_step<0x142, 0xA>(x);
    x = dpp_umin_step<0x143, 0xC>(x);
    return (unsigned)__builtin_amdgcn_readlane((int)x, 63);
}

// ---------------------------------------------------------------- fused prep (blocks 0..511) + KNN (blocks 512..2559)
__global__ __launch_bounds__(256) void prep_knn(const float* __restrict__ f, const float* __restrict__ Wf,
                                                const float* __restrict__ xyz, const float* __restrict__ Wg,
                                                const float* __restrict__ W_q, const float* __restrict__ W_k,
                                                const float* __restrict__ W_v, const float* __restrict__ W_fus,
                                                float* __restrict__ X, float* __restrict__ A,
                                                ushort* __restrict__ Wb, float* __restrict__ sums,
                                                int* __restrict__ idx) {
    __shared__ float4 SXQ[2048];
    int t = threadIdx.x;
    int blk = blockIdx.x;
    if (blk < 512) {
        // ======== prep path ========
        float* As = (float*)SXQ;
        float* Ws = As + 16*68;
        int bx = blk & 127, by = blk >> 7;
        if (by == 0 && bx < 12) sums[bx*256 + t] = 0.f;
        int gid = (by*128 + bx)*256 + t;
        for (int i = gid; i < 311296; i += 131072) {
            const float* Wsrc; int off;
            if (i < 65536)       { Wsrc = W_q;   off = i; }
            else if (i < 131072) { Wsrc = W_k;   off = i - 65536; }
            else if (i < 196608) { Wsrc = W_v;   off = i - 131072; }
            else                 { Wsrc = W_fus; off = i - 196608; }
            Wb[i] = f2bf(Wsrc[off]);
        }
        int r0 = bx * 64, n0 = by * 64;
        for (int e = t; e < 4096; e += 256) {
            int row = r0 + (e >> 6), c = n0 + (e & 63), cc = c & 127;
            float x = xyz[row*3], y = xyz[row*3+1], z = xyz[row*3+2];
            const float* w = Wg + cc*6;
            float s = (c < 128) ? ((w[3]*x + w[4]*y) + w[5]*z)
                                : (((w[0]-w[3])*x + (w[1]-w[4])*y) + (w[2]-w[5])*z);
            A[(size_t)row*256 + c] = s;
        }
        int b = r0 >> 11, nbase = r0 & 2047;
        int tx = t & 15, ty = t >> 4;
        float acc[4][4];
#pragma unroll
        for (int i = 0; i < 4; i++)
#pragma unroll
            for (int j = 0; j < 4; j++) acc[i][j] = 0.f;
        int m64 = t & 63, kg = t >> 6;
        int lk = t & 15, lm = t >> 4;
        for (int k0 = 0; k0 < 64; k0 += 16) {
#pragma unroll
            for (int p = 0; p < 4; p++) {
                int k = kg*4 + p;
                As[k*68 + m64] = f[(size_t)b*CIN*NPTS + (size_t)(k0 + k)*NPTS + nbase + m64];
            }
#pragma unroll
            for (int i2 = 0; i2 < 4; i2++) {
                int cg = n0 + lm + 16*i2;
                Ws[lk*68 + lm + 16*i2] = Wf[(size_t)(cg & 127)*128 + (cg >> 7)*64 + k0 + lk];
            }
            __syncthreads();
#pragma unroll
            for (int kq = 0; kq < 16; kq++) {
                float4 a  = *(const float4*)&As[kq*68 + 4*ty];
                float4 b4 = *(const float4*)&Ws[kq*68 + 4*tx];
                float av[4] = {a.x, a.y, a.z, a.w};
                float bv[4] = {b4.x, b4.y, b4.z, b4.w};
#pragma unroll
                for (int i = 0; i < 4; i++)
#pragma unroll
                    for (int j = 0; j < 4; j++) acc[i][j] = fmaf(av[i], bv[j], acc[i][j]);
            }
            __syncthreads();
        }
#pragma unroll
        for (int i = 0; i < 4; i++)
#pragma unroll
            for (int j = 0; j < 4; j++)
                X[(size_t)(r0 + 4*ty + i)*256 + n0 + 4*tx + j] = acc[i][j];
        return;
    }
    // ======== KNN path ========
    int kb = blk - 512;
    int b = kb >> 9;
    int g = kb & 511;
    for (int m = t; m < NPTS; m += 256) {
        float x = xyz[(size_t)b*NPTS*3 + m*3];
        float y = xyz[(size_t)b*NPTS*3 + m*3 + 1];
        float z = xyz[(size_t)b*NPTS*3 + m*3 + 2];
        SXQ[m] = make_float4(x, y, z, (x*x + y*y) + z*z);
    }
    __syncthreads();
    int w = t >> 6, lane = t & 63;
    int n = g*4 + w;
    float4 q4 = SXQ[n];
    float qx = q4.x, qy = q4.y, qz = q4.z, sqn = q4.w;
    unsigned key[32];
#pragma unroll
    for (int i = 0; i < 32; i++) {
        int m = lane + (i << 6);
        float4 p = SXQ[m];
        float dt = (qx*p.x + qy*p.y) + qz*p.z;
        float d2 = fmaxf((sqn + p.w) - 2.0f*dt, 0.f);
        key[i] = (__float_as_uint(d2) & 0xFFFFF800u) | (unsigned)m;
    }
    unsigned winkey = 0xFFFFFFFFu;
    for (int kk = 0; kk < 32; kk++) {
        unsigned lv = key[0];
#pragma unroll
        for (int i = 1; i < 32; i++) lv = (key[i] < lv) ? key[i] : lv;
        unsigned win = wave_min_u32(lv);
        if (lane == kk) winkey = win;
        unsigned widx = win & 2047u;
        int slot = (int)(widx >> 6);
        bool own = (lane == (int)(widx & 63u));
#pragma unroll
        for (int i = 0; i < 32; i++)
            if (i == slot && own) key[i] = 0xFFFFFFFFu;
    }
    double d2r;
    int mr;
    {
        double qx64 = (double)qx, qy64 = (double)qy, qz64 = (double)qz;
        double sqn64 = qx64*qx64 + qy64*qy64 + qz64*qz64;
        if (lane < 32) {
            mr = (int)(winkey & 2047u);
            float4 p = SXQ[mr];
            double x = (double)p.x, y = (double)p.y, z = (double)p.z;
            double sqm = x*x + y*y + z*z;
            double dt  = qx64*x + qy64*y + qz64*z;
            d2r = (sqn64 + sqm) - 2.0*dt;
        } else {
            d2r = INFINITY; mr = 0x7FFFFFFF;
        }
    }
#pragma unroll
    for (int k = 2; k <= 32; k <<= 1) {
#pragma unroll
        for (int j = k >> 1; j > 0; j >>= 1) {
            double od = __shfl_xor(d2r, j, 64);
            int    om = __shfl_xor(mr, j, 64);
            bool up    = ((lane & k) == 0);
            bool lower = ((lane & j) == 0);
            bool oless = (od < d2r) || (od == d2r && om < mr);
            bool keepOther = up ? (lower ? oless : !oless) : (lower ? !oless : oless);
            if (keepOther) { d2r = od; mr = om; }
        }
    }
    if (lane < KNBR)
        idx[((size_t)b*NPTS + n)*KNBR + lane] = mr;
}

// ---------------------------------------------------------------- stats + sign-selected extreme over K
__global__ __launch_bounds__(256) void stats_gf(const float* __restrict__ geoBC, const float* __restrict__ featAC,
                                                const int* __restrict__ idx, const float* __restrict__ g_geo,
                                                const float* __restrict__ g_feat,
                                                float* __restrict__ sums, float* __restrict__ xsel) {
    int c = threadIdx.x;
    int cc = c & 127;
    const float* base = (c < 128) ? geoBC : featAC;
    bool wantmax = ((c < 128) ? g_geo[cc] : g_feat[cc]) >= 0.f;
    float s = 0.f, ss = 0.f;
    int r0 = blockIdx.x * 32;
    for (int r = r0; r < r0 + 32; r++) {
        int b = r >> 11;
        float ctr = base[(size_t)r*256 + 128 + cc];
        float mx = -1e30f, mn = 1e30f;
        const int* ip = idx + (size_t)r*KNBR;
        for (int kk = 0; kk < KNBR; kk++) {
            int j = ip[kk];
            float xv = ctr + base[((size_t)(b*NPTS + j))*256 + cc];
            mx = fmaxf(mx, xv); mn = fminf(mn, xv);
            s += xv; ss += xv*xv;
        }
        xsel[(size_t)r*256 + c] = wantmax ? mx : mn;
    }
    atomicAdd(&sums[c], s);
    atomicAdd(&sums[256 + c], ss);
}

// ---------------------------------------------------------------- feature_ = relu(affine(xsel)) with inline BN finalize; + bn1 stats
__global__ __launch_bounds__(256) void feature_maxsel(const float* __restrict__ xsel, const float* __restrict__ sums,
                                                      const float* __restrict__ g_geo, const float* __restrict__ b_geo,
                                                      const float* __restrict__ g_feat, const float* __restrict__ b_feat,
                                                      float* __restrict__ feat, float* __restrict__ sums_bn1) {
    int c = threadIdx.x;
    const float inv = 1.0f / (float)(ROWS*KNBR);
    float mean = sums[c]*inv;
    float var  = sums[256+c]*inv - mean*mean;
    float g  = (c < 128) ? g_geo[c] : g_feat[c-128];
    float bb = (c < 128) ? b_geo[c] : b_feat[c-128];
    float sc = g / sqrtf(var + 1e-5f);
    float tt = bb - mean*sc;
    float s = 0.f, ss = 0.f;
    int r0 = blockIdx.x*32;
    for (int r = r0; r < r0+32; r++) {
        size_t i = (size_t)r*256 + c;
        float y = fmaxf(fmaf(sc, xsel[i], tt), 0.f);
        feat[i] = y; s += y; ss += y*y;
    }
    atomicAdd(&sums_bn1[c], s); atomicAdd(&sums_bn1[256+c], ss);
}

// ---------------------------------------------------------------- q/k/v GEMM via bf16 MFMA; inline bn1 finalize on A
__global__ __launch_bounds__(256) void gemm_qkv(const float* __restrict__ Af, const float* __restrict__ sums_in,
                                                const float* __restrict__ g_bn, const float* __restrict__ b_bn,
                                                const ushort* __restrict__ Wb,
                                                float* __restrict__ QKVF, float* __restrict__ sums) {
    __shared__ float bns[2][256];
    __shared__ float red[4][256][2];
    int t = threadIdx.x;
    int r0 = blockIdx.x * 64, g = blockIdx.y;
    int w = t >> 6, lane = t & 63;
    int r15 = lane & 15, quad = lane >> 4;
    {
        float mean = sums_in[512 + t] * (1.0f/(float)ROWS);
        float var  = sums_in[768 + t] * (1.0f/(float)ROWS) - mean*mean;
        float sc = g_bn[t] / sqrtf(var + 1e-5f);
        bns[0][t] = sc;
        bns[1][t] = b_bn[t] - mean*sc;
    }
    __syncthreads();
    short8 aq[8];
    {
        const float* ap = Af + (size_t)(r0 + 16*w + r15)*256;
#pragma unroll
        for (int kc = 0; kc < 8; kc++) {
            int k0 = 32*kc + 8*quad;
            float4 a0 = *(const float4*)&ap[k0];
            float4 a1 = *(const float4*)&ap[k0+4];
            float4 s0 = *(const float4*)&bns[0][k0];
            float4 s1 = *(const float4*)&bns[0][k0+4];
            float4 h0 = *(const float4*)&bns[1][k0];
            float4 h1 = *(const float4*)&bns[1][k0+4];
            ushort u8[8];
            u8[0] = f2bf(fmaf(s0.x, a0.x, h0.x)); u8[1] = f2bf(fmaf(s0.y, a0.y, h0.y));
            u8[2] = f2bf(fmaf(s0.z, a0.z, h0.z)); u8[3] = f2bf(fmaf(s0.w, a0.w, h0.w));
            u8[4] = f2bf(fmaf(s1.x, a1.x, h1.x)); u8[5] = f2bf(fmaf(s1.y, a1.y, h1.y));
            u8[6] = f2bf(fmaf(s1.z, a1.z, h1.z)); u8[7] = f2bf(fmaf(s1.w, a1.w, h1.w));
            aq[kc] = *(short8*)u8;
        }
    }
    floatx4 zero4 = {0.f, 0.f, 0.f, 0.f};
    floatx4 acc[16];
#pragma unroll
    for (int st = 0; st < 16; st++) acc[st] = zero4;
    const ushort* wbase = Wb + (size_t)g*65536 + (size_t)r15*256 + 8*quad;
#pragma unroll
    for (int st = 0; st < 16; st++) {
        const ushort* wp = wbase + (size_t)(16*st)*256;
#pragma unroll
        for (int kc = 0; kc < 8; kc++) {
            short8 bf = *(const short8*)(wp + 32*kc);
            acc[st] = __builtin_amdgcn_mfma_f32_16x16x32_bf16(aq[kc], bf, acc[st], 0, 0, 0);
        }
    }
#pragma unroll
    for (int st = 0; st < 16; st++) {
        float s  = (acc[st][0] + acc[st][1]) + (acc[st][2] + acc[st][3]);
        float q2 = (acc[st][0]*acc[st][0] + acc[st][1]*acc[st][1]) +
                   (acc[st][2]*acc[st][2] + acc[st][3]*acc[st][3]);
        s  += __shfl_xor(s, 16, 64);  s  += __shfl_xor(s, 32, 64);
        q2 += __shfl_xor(q2, 16, 64); q2 += __shfl_xor(q2, 32, 64);
        if (lane < 16) { red[w][16*st + r15][0] = s; red[w][16*st + r15][1] = q2; }
#pragma unroll
        for (int reg = 0; reg < 4; reg++)
            QKVF[(size_t)(r0 + 16*w + 4*quad + reg)*768 + g*256 + 16*st + r15] = acc[st][reg];
    }
    __syncthreads();
    {
        float s = red[0][t][0] + red[1][t][0] + red[2][t][0] + red[3][t][0];
        float q = red[0][t][1] + red[1][t][1] + red[2][t][1] + red[3][t][1];
        atomicAdd(&sums[1024 + g*512 + t], s);
        atomicAdd(&sums[1024 + g*512 + 256 + t], q);
    }
}

// ---------------------------------------------------------------- affine+relu+bf16 (inline qkv BN finalize): q/k row-major (q scaled by log2e), v transposed
__global__ __launch_bounds__(256) void affine_qkv(const float* __restrict__ QKVF, const float* __restrict__ sums,
                                                  const float* __restrict__ g_q, const float* __restrict__ b_q,
                                                  const float* __restrict__ g_k, const float* __restrict__ b_k,
                                                  const float* __restrict__ g_v, const float* __restrict__ b_v,
                                                  ushort* __restrict__ qk, ushort* __restrict__ vt) {
    __shared__ float sts[6][256];
    __shared__ ushort tile[64][72];
    int t = threadIdx.x;
    {
        const float* gs[3] = {g_q, g_k, g_v};
        const float* bs[3] = {b_q, b_k, b_v};
#pragma unroll
        for (int g = 0; g < 3; g++) {
            float mean = sums[1024 + g*512 + t] * (1.0f/(float)ROWS);
            float var  = sums[1024 + g*512 + 256 + t] * (1.0f/(float)ROWS) - mean*mean;
            float sc = gs[g][t] / sqrtf(var + 1e-5f);
            float sh = bs[g][t] - mean*sc;
            if (g == 0) { sc *= LOG2E; sh *= LOG2E; }   // exp2-domain softmax
            sts[2*g][t] = sc;
            sts[2*g+1][t] = sh;
        }
    }
    __syncthreads();
    int r0 = blockIdx.x * 64, c0 = blockIdx.y * 64;
    int b = r0 >> 11, nbase = r0 & 2047;
    if (c0 < 512) {
#pragma unroll
        for (int rep = 0; rep < 16; rep++) {
            int e = t + 256*rep;
            int row = e >> 6, c = e & 63;
            int col = c0 + c, g = col >> 8, cc = col & 255;
            float v = QKVF[(size_t)(r0 + row)*768 + col];
            v = fmaxf(fmaf(sts[2*g][cc], v, sts[2*g+1][cc]), 0.f);
            qk[(size_t)(r0 + row)*512 + col] = f2bf(v);
        }
    } else {
#pragma unroll
        for (int rep = 0; rep < 16; rep++) {
            int e = t + 256*rep;
            int row = e >> 6, c = e & 63;
            int col = c0 + c, cc = col & 255;
            float v = QKVF[(size_t)(r0 + row)*768 + col];
            v = fmaxf(fmaf(sts[4][cc], v, sts[5][cc]), 0.f);
            tile[c][row] = f2bf(v);
        }
        __syncthreads();
#pragma unroll
        for (int rep = 0; rep < 16; rep++) {
            int e = t + 256*rep;
            int cc = e >> 6, nn = e & 63;
            vt[((size_t)(b*256 + (c0 - 512) + cc))*2048 + nbase + nn] = tile[cc][nn];
        }
    }
}

// ---------------------------------------------------------------- MFMA bf16 flash attention (exp2 domain), 2 Q-tiles/block, DPP softmax
__global__ __launch_bounds__(256) void attn2(const ushort* __restrict__ qk, const ushort* __restrict__ vt,
                                             float* __restrict__ obuf) {
    __shared__ ushort Ksh[64*72];
    __shared__ ushort Vts[64*72];
    __shared__ ushort Psh[128*72];
    int h = blockIdx.y, b = blockIdx.z;
    int r0 = blockIdx.x * 128;
    int t = threadIdx.x;
    int w = t >> 6, lane = t & 63;
    int r15 = lane & 15, quad = lane >> 4;
    size_t rowbase = (size_t)b*NPTS;
    int hoff = h*DSH;

    short8 aq[2][2];
#pragma unroll
    for (int u = 0; u < 2; u++)
#pragma unroll
        for (int s = 0; s < 2; s++)
            aq[u][s] = *(const short8*)(qk + (rowbase + r0 + 64*u + 16*w + r15)*512 + hoff + 32*s + 8*quad);

    floatx4 zero4 = {0.f, 0.f, 0.f, 0.f};
    floatx4 oacc[2][4];
    float mrun[2][4], lrun[2][4];
#pragma unroll
    for (int u = 0; u < 2; u++)
#pragma unroll
        for (int i = 0; i < 4; i++) { oacc[u][i] = zero4; mrun[u][i] = -1e30f; lrun[u][i] = 0.f; }

    for (int m0 = 0; m0 < NPTS; m0 += 64) {
#pragma unroll
        for (int rep = 0; rep < 2; rep++) {
            int e = t + 256*rep;
            int rr = e >> 3, c = e & 7;
            *(uint4*)&Ksh[rr*72 + 8*c] =
                *(const uint4*)(qk + (rowbase + m0 + rr)*512 + 256 + hoff + 8*c);
            *(uint4*)&Vts[rr*72 + 8*c] =
                *(const uint4*)(vt + ((size_t)(b*256 + hoff + rr))*2048 + m0 + 8*c);
        }
        __syncthreads();

        floatx4 sacc[2][4];
#pragma unroll
        for (int u = 0; u < 2; u++)
#pragma unroll
            for (int tt = 0; tt < 4; tt++) sacc[u][tt] = zero4;
#pragma unroll
        for (int tt = 0; tt < 4; tt++) {
            int key = 16*tt + r15;
#pragma unroll
            for (int s = 0; s < 2; s++) {
                short8 kf = *(const short8*)&Ksh[key*72 + 32*s + 8*quad];
#pragma unroll
                for (int u = 0; u < 2; u++)
                    sacc[u][tt] = __builtin_amdgcn_mfma_f32_16x16x32_bf16(aq[u][s], kf, sacc[u][tt], 0, 0, 0);
            }
        }

        float pm[2][4][4];
#pragma unroll
        for (int u = 0; u < 2; u++)
#pragma unroll
            for (int reg = 0; reg < 4; reg++) {
                float rmax = fmaxf(fmaxf(sacc[u][0][reg], sacc[u][1][reg]),
                                   fmaxf(sacc[u][2][reg], sacc[u][3][reg]));
                rmax = dpp_max16(rmax);
                float mnew = fmaxf(mrun[u][reg], rmax);
                float alpha = exp2f(mrun[u][reg] - mnew);
                float rs = 0.f;
#pragma unroll
                for (int tt = 0; tt < 4; tt++) {
                    float p = exp2f(sacc[u][tt][reg] - mnew);
                    pm[u][tt][reg] = p; rs += p;
                }
                rs = dpp_sum16(rs);
                lrun[u][reg] = lrun[u][reg]*alpha + rs;
                mrun[u][reg] = mnew;
#pragma unroll
                for (int td = 0; td < 4; td++) oacc[u][td][reg] *= alpha;
            }

#pragma unroll
        for (int u = 0; u < 2; u++)
#pragma unroll
            for (int reg = 0; reg < 4; reg++) {
                int row = 64*u + 16*w + 4*quad + reg;
#pragma unroll
                for (int tt = 0; tt < 4; tt++)
                    Psh[row*72 + 16*tt + r15] = f2bf(pm[u][tt][reg]);
            }
        __syncthreads();

#pragma unroll
        for (int s = 0; s < 2; s++) {
            short8 pf[2];
#pragma unroll
            for (int u = 0; u < 2; u++)
                pf[u] = *(const short8*)&Psh[(64*u + 16*w + r15)*72 + 32*s + 8*quad];
#pragma unroll
            for (int td = 0; td < 4; td++) {
                short8 vf = *(const short8*)&Vts[(16*td + r15)*72 + 32*s + 8*quad];
#pragma unroll
                for (int u = 0; u < 2; u++)
                    oacc[u][td] = __builtin_amdgcn_mfma_f32_16x16x32_bf16(pf[u], vf, oacc[u][td], 0, 0, 0);
            }
        }
        __syncthreads();
    }

#pragma unroll
    for (int u = 0; u < 2; u++)
#pragma unroll
        for (int reg = 0; reg < 4; reg++) {
            int grow = r0 + 64*u + 16*w + 4*quad + reg;
            float invl = 1.f / lrun[u][reg];
#pragma unroll
            for (int td = 0; td < 4; td++)
                obuf[(rowbase + grow)*(size_t)(NHEADS*WCH) + h*WCH + 16*td + r15] = oacc[u][td][reg]*invl;
        }
}

// ---------------------------------------------------------------- fus GEMM (bf16 MFMA); A = normalized attention output; bias; stats
__global__ __launch_bounds__(256) void gemm_fus(const float* __restrict__ OBUF, const ushort* __restrict__ Wb,
                                                const float* __restrict__ bias, float* __restrict__ C,
                                                float* __restrict__ sums) {
    __shared__ float red[4][128][2];
    int t = threadIdx.x;
    int r0 = blockIdx.x * 64, n0 = blockIdx.y * 128;
    int w = t >> 6, lane = t & 63;
    int r15 = lane & 15, quad = lane >> 4;
    int arow = 16*w + r15;
    short8 aq[14];
    {
        const float* p0 = OBUF + (size_t)(r0 + arow)*448;
#pragma unroll
        for (int kc = 0; kc < 14; kc++) {
            int k0 = 32*kc + 8*quad;
            float4 x0 = *(const float4*)&p0[k0];
            float4 y0 = *(const float4*)&p0[k0+4];
            ushort u8[8];
            u8[0] = f2bf(x0.x); u8[1] = f2bf(x0.y);
            u8[2] = f2bf(x0.z); u8[3] = f2bf(x0.w);
            u8[4] = f2bf(y0.x); u8[5] = f2bf(y0.y);
            u8[6] = f2bf(y0.z); u8[7] = f2bf(y0.w);
            aq[kc] = *(short8*)u8;
        }
    }
    floatx4 zero4 = {0.f, 0.f, 0.f, 0.f};
    floatx4 acc[8];
#pragma unroll
    for (int st = 0; st < 8; st++) acc[st] = zero4;
    const ushort* wbase = Wb + 196608 + (size_t)(n0 + r15)*448 + 8*quad;
#pragma unroll
    for (int st = 0; st < 8; st++) {
        const ushort* wp = wbase + (size_t)(16*st)*448;
#pragma unroll
        for (int kc = 0; kc < 14; kc++) {
            short8 bf = *(const short8*)(wp + 32*kc);
            acc[st] = __builtin_amdgcn_mfma_f32_16x16x32_bf16(aq[kc], bf, acc[st], 0, 0, 0);
        }
    }
#pragma unroll
    for (int st = 0; st < 8; st++) {
        int col = n0 + 16*st + r15;
        float bi = bias[col];
        float v0 = acc[st][0] + bi, v1 = acc[st][1] + bi, v2 = acc[st][2] + bi, v3 = acc[st][3] + bi;
        float s  = (v0 + v1) + (v2 + v3);
        float q2 = (v0*v0 + v1*v1) + (v2*v2 + v3*v3);
        s  += __shfl_xor(s, 16, 64);  s  += __shfl_xor(s, 32, 64);
        q2 += __shfl_xor(q2, 16, 64); q2 += __shfl_xor(q2, 32, 64);
        if (lane < 16) { red[w][16*st + r15][0] = s; red[w][16*st + r15][1] = q2; }
        C[(size_t)(r0 + 16*w + 4*quad + 0)*256 + col] = v0;
        C[(size_t)(r0 + 16*w + 4*quad + 1)*256 + col] = v1;
        C[(size_t)(r0 + 16*w + 4*quad + 2)*256 + col] = v2;
        C[(size_t)(r0 + 16*w + 4*quad + 3)*256 + col] = v3;
    }
    __syncthreads();
    {
        int col = t >> 1, which = t & 1;
        float v = red[0][col][which] + red[1][col][which] + red[2][col][which] + red[3][col][which];
        atomicAdd(&sums[2560 + which*256 + n0 + col], v);
    }
}

// ---------------------------------------------------------------- fused: fus-BN+relu+residual+LN (per-row) + MLP GEMM + residual + transposed out
__global__ __launch_bounds__(256) void gemm_mlp_ln(const float* __restrict__ FUSP, const float* __restrict__ A,
                                                   const float* __restrict__ sums,
                                                   const float* __restrict__ g_fus, const float* __restrict__ b_fus,
                                                   const float* __restrict__ g_ln, const float* __restrict__ b_ln,
                                                   const float* __restrict__ W, const float* __restrict__ bias,
                                                   float* __restrict__ outp) {
    __shared__ float Ys[256][68];    // y (LN out), k-major: Ys[c][row]
    __shared__ float FFs[64][65];    // feature__ tile (cols n0..n0+63)
    __shared__ float Ws[16][68];
    __shared__ float tr[64][65];
    __shared__ float SC[256], SH[256], GL[256], BL[256];
    int t = threadIdx.x;
    int r0 = blockIdx.x*64, n0 = blockIdx.y*64;
    {
        float mean0 = sums[2560 + t] * (1.0f/(float)ROWS);
        float var0  = sums[2560 + 256 + t] * (1.0f/(float)ROWS) - mean0*mean0;
        float sc = g_fus[t] / sqrtf(var0 + 1e-5f);
        SC[t] = sc; SH[t] = b_fus[t] - mean0*sc;
        GL[t] = g_ln[t]; BL[t] = b_ln[t];
    }
    __syncthreads();
    int row = t >> 2, seg = t & 3;
    size_t rb = (size_t)(r0 + row)*256;
    float4 vv[16];
    float s = 0.f, ss = 0.f;
#pragma unroll
    for (int j = 0; j < 16; j++) {
        int c = seg*64 + 4*j;
        float4 fp = *(const float4*)&FUSP[rb + c];
        float4 fe = *(const float4*)&A[rb + c];
        float4 sc4 = *(const float4*)&SC[c];
        float4 sh4 = *(const float4*)&SH[c];
        float4 v;
        v.x = fmaxf(fmaf(sc4.x, fp.x, sh4.x), 0.f) + fe.x;
        v.y = fmaxf(fmaf(sc4.y, fp.y, sh4.y), 0.f) + fe.y;
        v.z = fmaxf(fmaf(sc4.z, fp.z, sh4.z), 0.f) + fe.z;
        v.w = fmaxf(fmaf(sc4.w, fp.w, sh4.w), 0.f) + fe.w;
        vv[j] = v;
        s  += (v.x + v.y) + (v.z + v.w);
        ss += (v.x*v.x + v.y*v.y) + (v.z*v.z + v.w*v.w);
        if (seg == blockIdx.y) *(float4*)&FFs[row][4*j] = v;
    }
    s  += __shfl_xor(s, 1, 64);  s  += __shfl_xor(s, 2, 64);
    ss += __shfl_xor(ss, 1, 64); ss += __shfl_xor(ss, 2, 64);
    float mean = s * (1.f/256.f);
    float var  = ss * (1.f/256.f) - mean*mean;
    float rin  = 1.f/sqrtf(var + 1e-5f);
#pragma unroll
    for (int j = 0; j < 16; j++) {
        int c = seg*64 + 4*j;
        float4 gl = *(const float4*)&GL[c];
        float4 bl = *(const float4*)&BL[c];
        float4 v = vv[j];
        Ys[c+0][row] = (v.x - mean)*rin*gl.x + bl.x;
        Ys[c+1][row] = (v.y - mean)*rin*gl.y + bl.y;
        Ys[c+2][row] = (v.z - mean)*rin*gl.z + bl.z;
        Ys[c+3][row] = (v.w - mean)*rin*gl.w + bl.w;
    }
    __syncthreads();
    // GEMM: y[64rows x 256] * W_mlp[n0..n0+63][256]^T
    int tx = t & 15, ty = t >> 4;
    int lk = t & 15, lm = t >> 4;
    float acc[4][4];
#pragma unroll
    for (int i = 0; i < 4; i++)
#pragma unroll
        for (int j = 0; j < 4; j++) acc[i][j] = 0.f;
    for (int k0 = 0; k0 < 256; k0 += 16) {
#pragma unroll
        for (int i2 = 0; i2 < 4; i2++)
            Ws[lk][lm + 16*i2] = W[(size_t)(n0 + lm + 16*i2)*256 + k0 + lk];
        __syncthreads();
#pragma unroll
        for (int kq = 0; kq < 16; kq++) {
            float4 a  = *(const float4*)&Ys[k0 + kq][4*ty];
            float4 b4 = *(const float4*)&Ws[kq][4*tx];
            float av[4] = {a.x, a.y, a.z, a.w};
            float bv[4] = {b4.x, b4.y, b4.z, b4.w};
#pragma unroll
            for (int i = 0; i < 4; i++)
#pragma unroll
                for (int j = 0; j < 4; j++) acc[i][j] = fmaf(av[i], bv[j], acc[i][j]);
        }
        __syncthreads();
    }
#pragma unroll
    for (int i = 0; i < 4; i++)
#pragma unroll
        for (int j = 0; j < 4; j++) {
            float v = acc[i][j] + bias[n0 + 4*tx + j] + FFs[4*ty + i][4*tx + j];
            tr[4*tx + j][4*ty + i] = v;
        }
    __syncthreads();
    int b = r0 >> 11, nbase = r0 & 2047;
#pragma unroll
    for (int rep = 0; rep < 16; rep++) {
        int e = t + 256*rep;
        int cl = e >> 6, nl = e & 63;
        outp[((size_t)(b*256 + n0 + cl))*2048 + nbase + nl] = tr[cl][nl];
    }
}

// ================================================================ host
extern "C" void kernel_launch(void* const* d_in, const int* in_sizes, int n_in,
                              void* d_out, int out_size, void* d_ws, size_t ws_size,
                              hipStream_t stream) {
    const float* xyz    = (const float*)d_in[0];
    const float* f      = (const float*)d_in[1];
    const float* W_geo  = (const float*)d_in[2];
    const float* g_geo  = (const float*)d_in[3];
    const float* b_geo  = (const float*)d_in[4];
    const float* W_feat = (const float*)d_in[5];
    const float* g_feat = (const float*)d_in[6];
    const float* b_feat = (const float*)d_in[7];
    const float* g_bn   = (const float*)d_in[8];
    const float* b_bn   = (const float*)d_in[9];
    const float* W_q    = (const float*)d_in[10];
    const float* g_q    = (const float*)d_in[11];
    const float* b_q    = (const float*)d_in[12];
    const float* W_k    = (const float*)d_in[13];
    const float* g_k    = (const float*)d_in[14];
    const float* b_k    = (const float*)d_in[15];
    const float* W_v    = (const float*)d_in[16];
    const float* g_v    = (const float*)d_in[17];
    const float* b_v    = (const float*)d_in[18];
    const float* W_fus  = (const float*)d_in[19];
    const float* bias_fus = (const float*)d_in[20];
    const float* g_fus  = (const float*)d_in[21];
    const float* b_fus  = (const float*)d_in[22];
    const float* g_ln   = (const float*)d_in[23];
    const float* b_ln   = (const float*)d_in[24];
    const float* W_mlp  = (const float*)d_in[25];
    const float* bias_mlp = (const float*)d_in[26];

    float* ws = (float*)d_ws;
    const size_t MBF = 262144;  // floats per MiB
    // Liveness (peak ~49.6 MiB):
    //  [0,1)    SUMS + IDX
    //  [1,9)    A: geoBC -> feature_ (live to gemm_mlp_ln)
    //  [9,17)   X (dead after stats_gf) -> QK16 bf16 (dead after attn) -> FUSP
    //  [17,41)  CSEL -> QKVF fp32 (dead after affine_qkv)
    //  [17,31)  OBUF fp32 (attn -> gemm_fus)
    //  [45,49)  VT16 bf16
    //  [49,49.6)  WB16 (q,k,v,fus bf16 weights)
    float* SUMS  = ws;
    int*   IDX   = (int*)(ws + 16384);
    float* A     = ws + 1*MBF;
    float* X     = ws + 9*MBF;
    ushort* QK16 = (ushort*)(ws + 9*MBF);
    float* FUSP  = ws + 9*MBF;
    float* CSEL  = ws + 17*MBF;
    float* QKVF  = ws + 17*MBF;
    float* OBUF  = ws + 17*MBF;
    ushort* VT16 = (ushort*)(ws + 45*MBF);
    ushort* WB16 = (ushort*)(ws + 49*MBF);

    prep_knn<<<2560, 256, 0, stream>>>(f, W_feat, xyz, W_geo, W_q, W_k, W_v, W_fus,
                                       X, A, WB16, SUMS, IDX);
    stats_gf<<<256, 256, 0, stream>>>(A, X, IDX, g_geo, g_feat, SUMS, CSEL);
    feature_maxsel<<<256, 256, 0, stream>>>(CSEL, SUMS, g_geo, b_geo, g_feat, b_feat, A, SUMS + 512);
    gemm_qkv<<<dim3(128, 3), 256, 0, stream>>>(A, SUMS, g_bn, b_bn, WB16, QKVF, SUMS);
    affine_qkv<<<dim3(128, 12), 256, 0, stream>>>(QKVF, SUMS, g_q, b_q, g_k, b_k, g_v, b_v, QK16, VT16);
    attn2<<<dim3(NPTS/128, NHEADS, NB), 256, 0, stream>>>(QK16, VT16, OBUF);
    gemm_fus<<<dim3(128, 2), 256, 0, stream>>>(OBUF, WB16, bias_fus, FUSP, SUMS);
    gemm_mlp_ln<<<dim3(128, 4), 256, 0, stream>>>(FUSP, A, SUMS, g_fus, b_fus, g_ln, b_ln,
                                                  W_mlp, bias_mlp, (float*)d_out);
}

// Round 14
// 433.627 us; speedup vs baseline: 1.0437x; 1.0437x over previous
//
#include <hip/hip_runtime.h>
#include <math.h>

#define NB    4
#define NPTS  2048
#define ROWS  (NB*NPTS)   // 8192
#define CIN   64
#define COUT  256
#define KNBR  21
#define NHEADS 7
#define WCH   64
#define DSH   32
#define LOG2E 1.4426950408889634f

typedef __attribute__((ext_vector_type(8))) short short8;
typedef __attribute__((ext_vector_type(4))) float floatx4;

#if __has_builtin(__builtin_amdgcn_exp2f)
#define EXP2(x) __builtin_amdgcn_exp2f(x)
#else
#define EXP2(x) __expf((x)*0.6931471805599453f)
#endif
#if __has_builtin(__builtin_amdgcn_rcpf)
#define RCP(x) __builtin_amdgcn_rcpf(x)
#else
#define RCP(x) (1.0f/(x))
#endif

__device__ __forceinline__ ushort f2bf(float x) {
    unsigned u = __float_as_uint(x);
    u += 0x7fffu + ((u >> 16) & 1u);   // RNE
    return (ushort)(u >> 16);
}

// DPP rotate within 16-lane row (VALU, no LDS pipe)
template<int N>
__device__ __forceinline__ float dpp_ror16(float x) {
    return __int_as_float(__builtin_amdgcn_update_dpp(
        0, __float_as_int(x), 0x120 | N, 0xF, 0xF, true));
}
__device__ __forceinline__ float dpp_max16(float x) {
    x = fmaxf(x, dpp_ror16<1>(x));
    x = fmaxf(x, dpp_ror16<2>(x));
    x = fmaxf(x, dpp_ror16<4>(x));
    x = fmaxf(x, dpp_ror16<8>(x));
    return x;
}
__device__ __forceinline__ float dpp_sum16(float x) {
    x += dpp_ror16<1>(x);
    x += dpp_ror16<2>(x);
    x += dpp_ror16<4>(x);
    x += dpp_ror16<8>(x);
    return x;
}

// wave64 u32 min-reduce via DPP chain; broadcast via readlane(63)
template<int CTRL, int RMASK>
__device__ __forceinline__ unsigned dpp_umin_step(unsigned x) {
    unsigned t = (unsigned)__builtin_amdgcn_update_dpp((int)x, (int)x, CTRL, RMASK, 0xF, false);
    return (t < x) ? t : x;
}
__device__ __forceinline__ unsigned wave_min_u32(unsigned x) {
    x = dpp_umin_step<0x111, 0xF>(x);
    x = dpp_umin_step<0x112, 0xF>(x);
    x = dpp_umin_step<0x114, 0xF>(x);
    x = dpp_umin_step<0x118, 0xF>(x);
    x = dpp_umin_step<0x142, 0xA>(x);
    x = dpp_umin_step<0x143, 0xC>(x);
    return (unsigned)__builtin_amdgcn_readlane((int)x, 63);
}

// ---------------------------------------------------------------- fused prep (blocks 0..511) + KNN (blocks 512..2559)
__global__ __launch_bounds__(256) void prep_knn(const float* __restrict__ f, const float* __restrict__ Wf,
                                                const float* __restrict__ xyz, const float* __restrict__ Wg,
                                                const float* __restrict__ W_q, const float* __restrict__ W_k,
                                                const float* __restrict__ W_v, const float* __restrict__ W_fus,
                                                float* __restrict__ X, float* __restrict__ A,
                                                ushort* __restrict__ Wb, float* __restrict__ sums,
                                                int* __restrict__ idx) {
    __shared__ float4 SXQ[2048];
    int t = threadIdx.x;
    int blk = blockIdx.x;
    if (blk < 512) {
        // ======== prep path ========
        float* As = (float*)SXQ;
        float* Ws = As + 16*68;
        int bx = blk & 127, by = blk >> 7;
        if (by == 0 && bx < 12) sums[bx*256 + t] = 0.f;
        int gid = (by*128 + bx)*256 + t;
        for (int i = gid; i < 311296; i += 131072) {
            const float* Wsrc; int off;
            if (i < 65536)       { Wsrc = W_q;   off = i; }
            else if (i < 131072) { Wsrc = W_k;   off = i - 65536; }
            else if (i < 196608) { Wsrc = W_v;   off = i - 131072; }
            else                 { Wsrc = W_fus; off = i - 196608; }
            Wb[i] = f2bf(Wsrc[off]);
        }
        int r0 = bx * 64, n0 = by * 64;
        for (int e = t; e < 4096; e += 256) {
            int row = r0 + (e >> 6), c = n0 + (e & 63), cc = c & 127;
            float x = xyz[row*3], y = xyz[row*3+1], z = xyz[row*3+2];
            const float* w = Wg + cc*6;
            float s = (c < 128) ? ((w[3]*x + w[4]*y) + w[5]*z)
                                : (((w[0]-w[3])*x + (w[1]-w[4])*y) + (w[2]-w[5])*z);
            A[(size_t)row*256 + c] = s;
        }
        int b = r0 >> 11, nbase = r0 & 2047;
        int tx = t & 15, ty = t >> 4;
        float acc[4][4];
#pragma unroll
        for (int i = 0; i < 4; i++)
#pragma unroll
            for (int j = 0; j < 4; j++) acc[i][j] = 0.f;
        int m64 = t & 63, kg = t >> 6;
        int lk = t & 15, lm = t >> 4;
        for (int k0 = 0; k0 < 64; k0 += 16) {
#pragma unroll
            for (int p = 0; p < 4; p++) {
                int k = kg*4 + p;
                As[k*68 + m64] = f[(size_t)b*CIN*NPTS + (size_t)(k0 + k)*NPTS + nbase + m64];
            }
#pragma unroll
            for (int i2 = 0; i2 < 4; i2++) {
                int cg = n0 + lm + 16*i2;
                Ws[lk*68 + lm + 16*i2] = Wf[(size_t)(cg & 127)*128 + (cg >> 7)*64 + k0 + lk];
            }
            __syncthreads();
#pragma unroll
            for (int kq = 0; kq < 16; kq++) {
                float4 a  = *(const float4*)&As[kq*68 + 4*ty];
                float4 b4 = *(const float4*)&Ws[kq*68 + 4*tx];
                float av[4] = {a.x, a.y, a.z, a.w};
                float bv[4] = {b4.x, b4.y, b4.z, b4.w};
#pragma unroll
                for (int i = 0; i < 4; i++)
#pragma unroll
                    for (int j = 0; j < 4; j++) acc[i][j] = fmaf(av[i], bv[j], acc[i][j]);
            }
            __syncthreads();
        }
#pragma unroll
        for (int i = 0; i < 4; i++)
#pragma unroll
            for (int j = 0; j < 4; j++)
                X[(size_t)(r0 + 4*ty + i)*256 + n0 + 4*tx + j] = acc[i][j];
        return;
    }
    // ======== KNN path ========
    int kb = blk - 512;
    int b = kb >> 9;
    int g = kb & 511;
    for (int m = t; m < NPTS; m += 256) {
        float x = xyz[(size_t)b*NPTS*3 + m*3];
        float y = xyz[(size_t)b*NPTS*3 + m*3 + 1];
        float z = xyz[(size_t)b*NPTS*3 + m*3 + 2];
        SXQ[m] = make_float4(x, y, z, (x*x + y*y) + z*z);
    }
    __syncthreads();
    int w = t >> 6, lane = t & 63;
    int n = g*4 + w;
    float4 q4 = SXQ[n];
    float qx = q4.x, qy = q4.y, qz = q4.z, sqn = q4.w;
    unsigned key[32];
#pragma unroll
    for (int i = 0; i < 32; i++) {
        int m = lane + (i << 6);
        float4 p = SXQ[m];
        float dt = (qx*p.x + qy*p.y) + qz*p.z;
        float d2 = fmaxf((sqn + p.w) - 2.0f*dt, 0.f);
        key[i] = (__float_as_uint(d2) & 0xFFFFF800u) | (unsigned)m;
    }
    unsigned winkey = 0xFFFFFFFFu;
    for (int kk = 0; kk < 32; kk++) {
        unsigned lv = key[0];
#pragma unroll
        for (int i = 1; i < 32; i++) lv = (key[i] < lv) ? key[i] : lv;
        unsigned win = wave_min_u32(lv);
        if (lane == kk) winkey = win;
        unsigned widx = win & 2047u;
        int slot = (int)(widx >> 6);
        bool own = (lane == (int)(widx & 63u));
#pragma unroll
        for (int i = 0; i < 32; i++)
            if (i == slot && own) key[i] = 0xFFFFFFFFu;
    }
    double d2r;
    int mr;
    {
        double qx64 = (double)qx, qy64 = (double)qy, qz64 = (double)qz;
        double sqn64 = qx64*qx64 + qy64*qy64 + qz64*qz64;
        if (lane < 32) {
            mr = (int)(winkey & 2047u);
            float4 p = SXQ[mr];
            double x = (double)p.x, y = (double)p.y, z = (double)p.z;
            double sqm = x*x + y*y + z*z;
            double dt  = qx64*x + qy64*y + qz64*z;
            d2r = (sqn64 + sqm) - 2.0*dt;
        } else {
            d2r = INFINITY; mr = 0x7FFFFFFF;
        }
    }
#pragma unroll
    for (int k = 2; k <= 32; k <<= 1) {
#pragma unroll
        for (int j = k >> 1; j > 0; j >>= 1) {
            double od = __shfl_xor(d2r, j, 64);
            int    om = __shfl_xor(mr, j, 64);
            bool up    = ((lane & k) == 0);
            bool lower = ((lane & j) == 0);
            bool oless = (od < d2r) || (od == d2r && om < mr);
            bool keepOther = up ? (lower ? oless : !oless) : (lower ? !oless : oless);
            if (keepOther) { d2r = od; mr = om; }
        }
    }
    if (lane < KNBR)
        idx[((size_t)b*NPTS + n)*KNBR + lane] = mr;
}

// ---------------------------------------------------------------- stats + sign-selected extreme over K
__global__ __launch_bounds__(256) void stats_gf(const float* __restrict__ geoBC, const float* __restrict__ featAC,
                                                const int* __restrict__ idx, const float* __restrict__ g_geo,
                                                const float* __restrict__ g_feat,
                                                float* __restrict__ sums, float* __restrict__ xsel) {
    int c = threadIdx.x;
    int cc = c & 127;
    const float* base = (c < 128) ? geoBC : featAC;
    bool wantmax = ((c < 128) ? g_geo[cc] : g_feat[cc]) >= 0.f;
    float s = 0.f, ss = 0.f;
    int r0 = blockIdx.x * 32;
    for (int r = r0; r < r0 + 32; r++) {
        int b = r >> 11;
        float ctr = base[(size_t)r*256 + 128 + cc];
        float mx = -1e30f, mn = 1e30f;
        const int* ip = idx + (size_t)r*KNBR;
        for (int kk = 0; kk < KNBR; kk++) {
            int j = ip[kk];
            float xv = ctr + base[((size_t)(b*NPTS + j))*256 + cc];
            mx = fmaxf(mx, xv); mn = fminf(mn, xv);
            s += xv; ss += xv*xv;
        }
        xsel[(size_t)r*256 + c] = wantmax ? mx : mn;
    }
    atomicAdd(&sums[c], s);
    atomicAdd(&sums[256 + c], ss);
}

// ---------------------------------------------------------------- feature_ = relu(affine(xsel)) with inline BN finalize; + bn1 stats
__global__ __launch_bounds__(256) void feature_maxsel(const float* __restrict__ xsel, const float* __restrict__ sums,
                                                      const float* __restrict__ g_geo, const float* __restrict__ b_geo,
                                                      const float* __restrict__ g_feat, const float* __restrict__ b_feat,
                                                      float* __restrict__ feat, float* __restrict__ sums_bn1) {
    int c = threadIdx.x;
    const float inv = 1.0f / (float)(ROWS*KNBR);
    float mean = sums[c]*inv;
    float var  = sums[256+c]*inv - mean*mean;
    float g  = (c < 128) ? g_geo[c] : g_feat[c-128];
    float bb = (c < 128) ? b_geo[c] : b_feat[c-128];
    float sc = g / sqrtf(var + 1e-5f);
    float tt = bb - mean*sc;
    float s = 0.f, ss = 0.f;
    int r0 = blockIdx.x*32;
    for (int r = r0; r < r0+32; r++) {
        size_t i = (size_t)r*256 + c;
        float y = fmaxf(fmaf(sc, xsel[i], tt), 0.f);
        feat[i] = y; s += y; ss += y*y;
    }
    atomicAdd(&sums_bn1[c], s); atomicAdd(&sums_bn1[256+c], ss);
}

// ---------------------------------------------------------------- q/k/v GEMM via bf16 MFMA; inline bn1 finalize on A
__global__ __launch_bounds__(256) void gemm_qkv(const float* __restrict__ Af, const float* __restrict__ sums_in,
                                                const float* __restrict__ g_bn, const float* __restrict__ b_bn,
                                                const ushort* __restrict__ Wb,
                                                float* __restrict__ QKVF, float* __restrict__ sums) {
    __shared__ float bns[2][256];
    __shared__ float red[4][256][2];
    int t = threadIdx.x;
    int r0 = blockIdx.x * 64, g = blockIdx.y;
    int w = t >> 6, lane = t & 63;
    int r15 = lane & 15, quad = lane >> 4;
    {
        float mean = sums_in[512 + t] * (1.0f/(float)ROWS);
        float var  = sums_in[768 + t] * (1.0f/(float)ROWS) - mean*mean;
        float sc = g_bn[t] / sqrtf(var + 1e-5f);
        bns[0][t] = sc;
        bns[1][t] = b_bn[t] - mean*sc;
    }
    __syncthreads();
    short8 aq[8];
    {
        const float* ap = Af + (size_t)(r0 + 16*w + r15)*256;
#pragma unroll
        for (int kc = 0; kc < 8; kc++) {
            int k0 = 32*kc + 8*quad;
            float4 a0 = *(const float4*)&ap[k0];
            float4 a1 = *(const float4*)&ap[k0+4];
            float4 s0 = *(const float4*)&bns[0][k0];
            float4 s1 = *(const float4*)&bns[0][k0+4];
            float4 h0 = *(const float4*)&bns[1][k0];
            float4 h1 = *(const float4*)&bns[1][k0+4];
            ushort u8[8];
            u8[0] = f2bf(fmaf(s0.x, a0.x, h0.x)); u8[1] = f2bf(fmaf(s0.y, a0.y, h0.y));
            u8[2] = f2bf(fmaf(s0.z, a0.z, h0.z)); u8[3] = f2bf(fmaf(s0.w, a0.w, h0.w));
            u8[4] = f2bf(fmaf(s1.x, a1.x, h1.x)); u8[5] = f2bf(fmaf(s1.y, a1.y, h1.y));
            u8[6] = f2bf(fmaf(s1.z, a1.z, h1.z)); u8[7] = f2bf(fmaf(s1.w, a1.w, h1.w));
            aq[kc] = *(short8*)u8;
        }
    }
    floatx4 zero4 = {0.f, 0.f, 0.f, 0.f};
    floatx4 acc[16];
#pragma unroll
    for (int st = 0; st < 16; st++) acc[st] = zero4;
    const ushort* wbase = Wb + (size_t)g*65536 + (size_t)r15*256 + 8*quad;
#pragma unroll
    for (int st = 0; st < 16; st++) {
        const ushort* wp = wbase + (size_t)(16*st)*256;
#pragma unroll
        for (int kc = 0; kc < 8; kc++) {
            short8 bf = *(const short8*)(wp + 32*kc);
            acc[st] = __builtin_amdgcn_mfma_f32_16x16x32_bf16(aq[kc], bf, acc[st], 0, 0, 0);
        }
    }
#pragma unroll
    for (int st = 0; st < 16; st++) {
        float s  = (acc[st][0] + acc[st][1]) + (acc[st][2] + acc[st][3]);
        float q2 = (acc[st][0]*acc[st][0] + acc[st][1]*acc[st][1]) +
                   (acc[st][2]*acc[st][2] + acc[st][3]*acc[st][3]);
        s  += __shfl_xor(s, 16, 64);  s  += __shfl_xor(s, 32, 64);
        q2 += __shfl_xor(q2, 16, 64); q2 += __shfl_xor(q2, 32, 64);
        if (lane < 16) { red[w][16*st + r15][0] = s; red[w][16*st + r15][1] = q2; }
#pragma unroll
        for (int reg = 0; reg < 4; reg++)
            QKVF[(size_t)(r0 + 16*w + 4*quad + reg)*768 + g*256 + 16*st + r15] = acc[st][reg];
    }
    __syncthreads();
    {
        float s = red[0][t][0] + red[1][t][0] + red[2][t][0] + red[3][t][0];
        float q = red[0][t][1] + red[1][t][1] + red[2][t][1] + red[3][t][1];
        atomicAdd(&sums[1024 + g*512 + t], s);
        atomicAdd(&sums[1024 + g*512 + 256 + t], q);
    }
}

// ---------------------------------------------------------------- affine+relu+bf16 (inline qkv BN finalize): q/k row-major (q scaled by log2e), v transposed
__global__ __launch_bounds__(256) void affine_qkv(const float* __restrict__ QKVF, const float* __restrict__ sums,
                                                  const float* __restrict__ g_q, const float* __restrict__ b_q,
                                                  const float* __restrict__ g_k, const float* __restrict__ b_k,
                                                  const float* __restrict__ g_v, const float* __restrict__ b_v,
                                                  ushort* __restrict__ qk, ushort* __restrict__ vt) {
    __shared__ float sts[6][256];
    __shared__ ushort tile[64][72];
    int t = threadIdx.x;
    {
        const float* gs[3] = {g_q, g_k, g_v};
        const float* bs[3] = {b_q, b_k, b_v};
#pragma unroll
        for (int g = 0; g < 3; g++) {
            float mean = sums[1024 + g*512 + t] * (1.0f/(float)ROWS);
            float var  = sums[1024 + g*512 + 256 + t] * (1.0f/(float)ROWS) - mean*mean;
            float sc = gs[g][t] / sqrtf(var + 1e-5f);
            float sh = bs[g][t] - mean*sc;
            if (g == 0) { sc *= LOG2E; sh *= LOG2E; }   // exp2-domain softmax
            sts[2*g][t] = sc;
            sts[2*g+1][t] = sh;
        }
    }
    __syncthreads();
    int r0 = blockIdx.x * 64, c0 = blockIdx.y * 64;
    int b = r0 >> 11, nbase = r0 & 2047;
    if (c0 < 512) {
#pragma unroll
        for (int rep = 0; rep < 16; rep++) {
            int e = t + 256*rep;
            int row = e >> 6, c = e & 63;
            int col = c0 + c, g = col >> 8, cc = col & 255;
            float v = QKVF[(size_t)(r0 + row)*768 + col];
            v = fmaxf(fmaf(sts[2*g][cc], v, sts[2*g+1][cc]), 0.f);
            qk[(size_t)(r0 + row)*512 + col] = f2bf(v);
        }
    } else {
#pragma unroll
        for (int rep = 0; rep < 16; rep++) {
            int e = t + 256*rep;
            int row = e >> 6, c = e & 63;
            int col = c0 + c, cc = col & 255;
            float v = QKVF[(size_t)(r0 + row)*768 + col];
            v = fmaxf(fmaf(sts[4][cc], v, sts[5][cc]), 0.f);
            tile[c][row] = f2bf(v);
        }
        __syncthreads();
#pragma unroll
        for (int rep = 0; rep < 16; rep++) {
            int e = t + 256*rep;
            int cc = e >> 6, nn = e & 63;
            vt[((size_t)(b*256 + (c0 - 512) + cc))*2048 + nbase + nn] = tile[cc][nn];
        }
    }
}

// ---------------------------------------------------------------- MFMA bf16 flash attention (exp2 domain, HW exp), 2 Q-tiles/block, DPP softmax
__global__ __launch_bounds__(256) void attn2(const ushort* __restrict__ qk, const ushort* __restrict__ vt,
                                             float* __restrict__ obuf) {
    __shared__ ushort Ksh[64*72];
    __shared__ ushort Vts[64*72];
    __shared__ ushort Psh[128*72];
    int h = blockIdx.y, b = blockIdx.z;
    int r0 = blockIdx.x * 128;
    int t = threadIdx.x;
    int w = t >> 6, lane = t & 63;
    int r15 = lane & 15, quad = lane >> 4;
    size_t rowbase = (size_t)b*NPTS;
    int hoff = h*DSH;

    short8 aq[2][2];
#pragma unroll
    for (int u = 0; u < 2; u++)
#pragma unroll
        for (int s = 0; s < 2; s++)
            aq[u][s] = *(const short8*)(qk + (rowbase + r0 + 64*u + 16*w + r15)*512 + hoff + 32*s + 8*quad);

    floatx4 zero4 = {0.f, 0.f, 0.f, 0.f};
    floatx4 oacc[2][4];
    float mrun[2][4], lrun[2][4];
#pragma unroll
    for (int u = 0; u < 2; u++)
#pragma unroll
        for (int i = 0; i < 4; i++) { oacc[u][i] = zero4; mrun[u][i] = -1e30f; lrun[u][i] = 0.f; }

    for (int m0 = 0; m0 < NPTS; m0 += 64) {
#pragma unroll
        for (int rep = 0; rep < 2; rep++) {
            int e = t + 256*rep;
            int rr = e >> 3, c = e & 7;
            *(uint4*)&Ksh[rr*72 + 8*c] =
                *(const uint4*)(qk + (rowbase + m0 + rr)*512 + 256 + hoff + 8*c);
            *(uint4*)&Vts[rr*72 + 8*c] =
                *(const uint4*)(vt + ((size_t)(b*256 + hoff + rr))*2048 + m0 + 8*c);
        }
        __syncthreads();

        floatx4 sacc[2][4];
#pragma unroll
        for (int u = 0; u < 2; u++)
#pragma unroll
            for (int tt = 0; tt < 4; tt++) sacc[u][tt] = zero4;
#pragma unroll
        for (int tt = 0; tt < 4; tt++) {
            int key = 16*tt + r15;
#pragma unroll
            for (int s = 0; s < 2; s++) {
                short8 kf = *(const short8*)&Ksh[key*72 + 32*s + 8*quad];
#pragma unroll
                for (int u = 0; u < 2; u++)
                    sacc[u][tt] = __builtin_amdgcn_mfma_f32_16x16x32_bf16(aq[u][s], kf, sacc[u][tt], 0, 0, 0);
            }
        }

        float pm[2][4][4];
#pragma unroll
        for (int u = 0; u < 2; u++)
#pragma unroll
            for (int reg = 0; reg < 4; reg++) {
                float rmax = fmaxf(fmaxf(sacc[u][0][reg], sacc[u][1][reg]),
                                   fmaxf(sacc[u][2][reg], sacc[u][3][reg]));
                rmax = dpp_max16(rmax);
                float mnew = fmaxf(mrun[u][reg], rmax);
                float alpha = EXP2(mrun[u][reg] - mnew);
                float rs = 0.f;
#pragma unroll
                for (int tt = 0; tt < 4; tt++) {
                    float p = EXP2(sacc[u][tt][reg] - mnew);
                    pm[u][tt][reg] = p; rs += p;
                }
                rs = dpp_sum16(rs);
                lrun[u][reg] = lrun[u][reg]*alpha + rs;
                mrun[u][reg] = mnew;
#pragma unroll
                for (int td = 0; td < 4; td++) oacc[u][td][reg] *= alpha;
            }

#pragma unroll
        for (int u = 0; u < 2; u++)
#pragma unroll
            for (int reg = 0; reg < 4; reg++) {
                int row = 64*u + 16*w + 4*quad + reg;
#pragma unroll
                for (int tt = 0; tt < 4; tt++)
                    Psh[row*72 + 16*tt + r15] = f2bf(pm[u][tt][reg]);
            }
        __syncthreads();

#pragma unroll
        for (int s = 0; s < 2; s++) {
            short8 pf[2];
#pragma unroll
            for (int u = 0; u < 2; u++)
                pf[u] = *(const short8*)&Psh[(64*u + 16*w + r15)*72 + 32*s + 8*quad];
#pragma unroll
            for (int td = 0; td < 4; td++) {
                short8 vf = *(const short8*)&Vts[(16*td + r15)*72 + 32*s + 8*quad];
#pragma unroll
                for (int u = 0; u < 2; u++)
                    oacc[u][td] = __builtin_amdgcn_mfma_f32_16x16x32_bf16(pf[u], vf, oacc[u][td], 0, 0, 0);
            }
        }
        __syncthreads();
    }

#pragma unroll
    for (int u = 0; u < 2; u++)
#pragma unroll
        for (int reg = 0; reg < 4; reg++) {
            int grow = r0 + 64*u + 16*w + 4*quad + reg;
            float invl = RCP(lrun[u][reg]);
#pragma unroll
            for (int td = 0; td < 4; td++)
                obuf[(rowbase + grow)*(size_t)(NHEADS*WCH) + h*WCH + 16*td + r15] = oacc[u][td][reg]*invl;
        }
}

// ---------------------------------------------------------------- fus GEMM (bf16 MFMA); A = normalized attention output; bias; stats
__global__ __launch_bounds__(256) void gemm_fus(const float* __restrict__ OBUF, const ushort* __restrict__ Wb,
                                                const float* __restrict__ bias, float* __restrict__ C,
                                                float* __restrict__ sums) {
    __shared__ float red[4][128][2];
    int t = threadIdx.x;
    int r0 = blockIdx.x * 64, n0 = blockIdx.y * 128;
    int w = t >> 6, lane = t & 63;
    int r15 = lane & 15, quad = lane >> 4;
    int arow = 16*w + r15;
    short8 aq[14];
    {
        const float* p0 = OBUF + (size_t)(r0 + arow)*448;
#pragma unroll
        for (int kc = 0; kc < 14; kc++) {
            int k0 = 32*kc + 8*quad;
            float4 x0 = *(const float4*)&p0[k0];
            float4 y0 = *(const float4*)&p0[k0+4];
            ushort u8[8];
            u8[0] = f2bf(x0.x); u8[1] = f2bf(x0.y);
            u8[2] = f2bf(x0.z); u8[3] = f2bf(x0.w);
            u8[4] = f2bf(y0.x); u8[5] = f2bf(y0.y);
            u8[6] = f2bf(y0.z); u8[7] = f2bf(y0.w);
            aq[kc] = *(short8*)u8;
        }
    }
    floatx4 zero4 = {0.f, 0.f, 0.f, 0.f};
    floatx4 acc[8];
#pragma unroll
    for (int st = 0; st < 8; st++) acc[st] = zero4;
    const ushort* wbase = Wb + 196608 + (size_t)(n0 + r15)*448 + 8*quad;
#pragma unroll
    for (int st = 0; st < 8; st++) {
        const ushort* wp = wbase + (size_t)(16*st)*448;
#pragma unroll
        for (int kc = 0; kc < 14; kc++) {
            short8 bf = *(const short8*)(wp + 32*kc);
            acc[st] = __builtin_amdgcn_mfma_f32_16x16x32_bf16(aq[kc], bf, acc[st], 0, 0, 0);
        }
    }
#pragma unroll
    for (int st = 0; st < 8; st++) {
        int col = n0 + 16*st + r15;
        float bi = bias[col];
        float v0 = acc[st][0] + bi, v1 = acc[st][1] + bi, v2 = acc[st][2] + bi, v3 = acc[st][3] + bi;
        float s  = (v0 + v1) + (v2 + v3);
        float q2 = (v0*v0 + v1*v1) + (v2*v2 + v3*v3);
        s  += __shfl_xor(s, 16, 64);  s  += __shfl_xor(s, 32, 64);
        q2 += __shfl_xor(q2, 16, 64); q2 += __shfl_xor(q2, 32, 64);
        if (lane < 16) { red[w][16*st + r15][0] = s; red[w][16*st + r15][1] = q2; }
        C[(size_t)(r0 + 16*w + 4*quad + 0)*256 + col] = v0;
        C[(size_t)(r0 + 16*w + 4*quad + 1)*256 + col] = v1;
        C[(size_t)(r0 + 16*w + 4*quad + 2)*256 + col] = v2;
        C[(size_t)(r0 + 16*w + 4*quad + 3)*256 + col] = v3;
    }
    __syncthreads();
    {
        int col = t >> 1, which = t & 1;
        float v = red[0][col][which] + red[1][col][which] + red[2][col][which] + red[3][col][which];
        atomicAdd(&sums[2560 + which*256 + n0 + col], v);
    }
}

// ---------------------------------------------------------------- fused: fus-BN+relu+residual+LN (per-row) + MLP GEMM + residual + transposed out
__global__ __launch_bounds__(256) void gemm_mlp_ln(const float* __restrict__ FUSP, const float* __restrict__ A,
                                                   const float* __restrict__ sums,
                                                   const float* __restrict__ g_fus, const float* __restrict__ b_fus,
                                                   const float* __restrict__ g_ln, const float* __restrict__ b_ln,
                                                   const float* __restrict__ W, const float* __restrict__ bias,
                                                   float* __restrict__ outp) {
    __shared__ float Ys[256][68];    // y (LN out), k-major: Ys[c][row]
    __shared__ float FFs[64][65];    // feature__ tile (cols n0..n0+63)
    __shared__ float Ws[16][68];
    __shared__ float tr[64][65];
    __shared__ float SC[256], SH[256], GL[256], BL[256];
    int t = threadIdx.x;
    int r0 = blockIdx.x*64, n0 = blockIdx.y*64;
    {
        float mean0 = sums[2560 + t] * (1.0f/(float)ROWS);
        float var0  = sums[2560 + 256 + t] * (1.0f/(float)ROWS) - mean0*mean0;
        float sc = g_fus[t] / sqrtf(var0 + 1e-5f);
        SC[t] = sc; SH[t] = b_fus[t] - mean0*sc;
        GL[t] = g_ln[t]; BL[t] = b_ln[t];
    }
    __syncthreads();
    int row = t >> 2, seg = t & 3;
    size_t rb = (size_t)(r0 + row)*256;
    float4 vv[16];
    float s = 0.f, ss = 0.f;
#pragma unroll
    for (int j = 0; j < 16; j++) {
        int c = seg*64 + 4*j;
        float4 fp = *(const float4*)&FUSP[rb + c];
        float4 fe = *(const float4*)&A[rb + c];
        float4 sc4 = *(const float4*)&SC[c];
        float4 sh4 = *(const float4*)&SH[c];
        float4 v;
        v.x = fmaxf(fmaf(sc4.x, fp.x, sh4.x), 0.f) + fe.x;
        v.y = fmaxf(fmaf(sc4.y, fp.y, sh4.y), 0.f) + fe.y;
        v.z = fmaxf(fmaf(sc4.z, fp.z, sh4.z), 0.f) + fe.z;
        v.w = fmaxf(fmaf(sc4.w, fp.w, sh4.w), 0.f) + fe.w;
        vv[j] = v;
        s  += (v.x + v.y) + (v.z + v.w);
        ss += (v.x*v.x + v.y*v.y) + (v.z*v.z + v.w*v.w);
        if (seg == blockIdx.y) *(float4*)&FFs[row][4*j] = v;
    }
    s  += __shfl_xor(s, 1, 64);  s  += __shfl_xor(s, 2, 64);
    ss += __shfl_xor(ss, 1, 64); ss += __shfl_xor(ss, 2, 64);
    float mean = s * (1.f/256.f);
    float var  = ss * (1.f/256.f) - mean*mean;
    float rin  = 1.f/sqrtf(var + 1e-5f);
#pragma unroll
    for (int j = 0; j < 16; j++) {
        int c = seg*64 + 4*j;
        float4 gl = *(const float4*)&GL[c];
        float4 bl = *(const float4*)&BL[c];
        float4 v = vv[j];
        Ys[c+0][row] = (v.x - mean)*rin*gl.x + bl.x;
        Ys[c+1][row] = (v.y - mean)*rin*gl.y + bl.y;
        Ys[c+2][row] = (v.z - mean)*rin*gl.z + bl.z;
        Ys[c+3][row] = (v.w - mean)*rin*gl.w + bl.w;
    }
    __syncthreads();
    // GEMM: y[64rows x 256] * W_mlp[n0..n0+63][256]^T
    int tx = t & 15, ty = t >> 4;
    int lk = t & 15, lm = t >> 4;
    float acc[4][4];
#pragma unroll
    for (int i = 0; i < 4; i++)
#pragma unroll
        for (int j = 0; j < 4; j++) acc[i][j] = 0.f;
    for (int k0 = 0; k0 < 256; k0 += 16) {
#pragma unroll
        for (int i2 = 0; i2 < 4; i2++)
            Ws[lk][lm + 16*i2] = W[(size_t)(n0 + lm + 16*i2)*256 + k0 + lk];
        __syncthreads();
#pragma unroll
        for (int kq = 0; kq < 16; kq++) {
            float4 a  = *(const float4*)&Ys[k0 + kq][4*ty];
            float4 b4 = *(const float4*)&Ws[kq][4*tx];
            float av[4] = {a.x, a.y, a.z, a.w};
            float bv[4] = {b4.x, b4.y, b4.z, b4.w};
#pragma unroll
            for (int i = 0; i < 4; i++)
#pragma unroll
                for (int j = 0; j < 4; j++) acc[i][j] = fmaf(av[i], bv[j], acc[i][j]);
        }
        __syncthreads();
    }
#pragma unroll
    for (int i = 0; i < 4; i++)
#pragma unroll
        for (int j = 0; j < 4; j++) {
            float v = acc[i][j] + bias[n0 + 4*tx + j] + FFs[4*ty + i][4*tx + j];
            tr[4*tx + j][4*ty + i] = v;
        }
    __syncthreads();
    int b = r0 >> 11, nbase = r0 & 2047;
#pragma unroll
    for (int rep = 0; rep < 16; rep++) {
        int e = t + 256*rep;
        int cl = e >> 6, nl = e & 63;
        outp[((size_t)(b*256 + n0 + cl))*2048 + nbase + nl] = tr[cl][nl];
    }
}

// ================================================================ host
extern "C" void kernel_launch(void* const* d_in, const int* in_sizes, int n_in,
                              void* d_out, int out_size, void* d_ws, size_t ws_size,
                              hipStream_t stream) {
    const float* xyz    = (const float*)d_in[0];
    const float* f      = (const float*)d_in[1];
    const float* W_geo  = (const float*)d_in[2];
    const float* g_geo  = (const float*)d_in[3];
    const float* b_geo  = (const float*)d_in[4];
    const float* W_feat = (const float*)d_in[5];
    const float* g_feat = (const float*)d_in[6];
    const float* b_feat = (const float*)d_in[7];
    const float* g_bn   = (const float*)d_in[8];
    const float* b_bn   = (const float*)d_in[9];
    const float* W_q    = (const float*)d_in[10];
    const float* g_q    = (const float*)d_in[11];
    const float* b_q    = (const float*)d_in[12];
    const float* W_k    = (const float*)d_in[13];
    const float* g_k    = (const float*)d_in[14];
    const float* b_k    = (const float*)d_in[15];
    const float* W_v    = (const float*)d_in[16];
    const float* g_v    = (const float*)d_in[17];
    const float* b_v    = (const float*)d_in[18];
    const float* W_fus  = (const float*)d_in[19];
    const float* bias_fus = (const float*)d_in[20];
    const float* g_fus  = (const float*)d_in[21];
    const float* b_fus  = (const float*)d_in[22];
    const float* g_ln   = (const float*)d_in[23];
    const float* b_ln   = (const float*)d_in[24];
    const float* W_mlp  = (const float*)d_in[25];
    const float* bias_mlp = (const float*)d_in[26];

    float* ws = (float*)d_ws;
    const size_t MBF = 262144;  // floats per MiB
    float* SUMS  = ws;
    int*   IDX   = (int*)(ws + 16384);
    float* A     = ws + 1*MBF;
    float* X     = ws + 9*MBF;
    ushort* QK16 = (ushort*)(ws + 9*MBF);
    float* FUSP  = ws + 9*MBF;
    float* CSEL  = ws + 17*MBF;
    float* QKVF  = ws + 17*MBF;
    float* OBUF  = ws + 17*MBF;
    ushort* VT16 = (ushort*)(ws + 45*MBF);
    ushort* WB16 = (ushort*)(ws + 49*MBF);

    prep_knn<<<2560, 256, 0, stream>>>(f, W_feat, xyz, W_geo, W_q, W_k, W_v, W_fus,
                                       X, A, WB16, SUMS, IDX);
    stats_gf<<<256, 256, 0, stream>>>(A, X, IDX, g_geo, g_feat, SUMS, CSEL);
    feature_maxsel<<<256, 256, 0, stream>>>(CSEL, SUMS, g_geo, b_geo, g_feat, b_feat, A, SUMS + 512);
    gemm_qkv<<<dim3(128, 3), 256, 0, stream>>>(A, SUMS, g_bn, b_bn, WB16, QKVF, SUMS);
    affine_qkv<<<dim3(128, 12), 256, 0, stream>>>(QKVF, SUMS, g_q, b_q, g_k, b_k, g_v, b_v, QK16, VT16);
    attn2<<<dim3(NPTS/128, NHEADS, NB), 256, 0, stream>>>(QK16, VT16, OBUF);
    gemm_fus<<<dim3(128, 2), 256, 0, stream>>>(OBUF, WB16, bias_fus, FUSP, SUMS);
    gemm_mlp_ln<<<dim3(128, 4), 256, 0, stream>>>(FUSP, A, SUMS, g_fus, b_fus, g_ln, b_ln,
                                                  W_mlp, bias_mlp, (float*)d_out);
}